// Round 1
// baseline (626.314 us; speedup 1.0000x reference)
//
#include <hip/hip_runtime.h>
#include <cstddef>
#include <cstdint>

// Problem constants (fixed by setup_inputs)
constexpr int B_SEG   = 4;
constexpr int N_C     = 4096;    // coarse points per batch
constexpr int M_F     = 16384;   // fine points per batch
constexpr int CIN     = 384;
constexpr int COUT    = 192;
constexpr int MT      = B_SEG * N_C;   // 16384 coarse rows
constexpr int MF      = B_SEG * M_F;   // 65536 fine rows
constexpr float LN_EPS = 1e-5f;

// ---------------------------------------------------------------------------
// K1: h = LN(feats) @ w2 + b2      [16384 x 384] -> [16384 x 192]
// Block: 256 threads, 32 rows. LN computed in registers (8 lanes/row),
// GEMM with K-chunked LDS staging (A transposed chunk 32x32, B chunk 32x192).
// Thread tile: 4 rows x 6 cols.
// ---------------------------------------------------------------------------
__global__ __launch_bounds__(256) void k1_ln_gemm(
    const float* __restrict__ feats, const float* __restrict__ ln_g,
    const float* __restrict__ ln_b, const float* __restrict__ w2,
    const float* __restrict__ b2, float* __restrict__ h)
{
  const int tid   = threadIdx.x;
  const int row   = tid >> 3;   // 0..31 (LN role)
  const int lane8 = tid & 7;    // 0..7
  const int tr    = tid >> 5;   // 0..7  (GEMM role: 4 rows each)
  const int tc    = tid & 31;   // 0..31 (6 cols each)
  const int row_g0 = blockIdx.x * 32;

  // ---- Phase 1: load row, LN stats, normalize into registers ----
  float4 va[12];
  const float* frow = feats + (size_t)(row_g0 + row) * CIN;
  float sum = 0.f, sumsq = 0.f;
#pragma unroll
  for (int c = 0; c < 12; ++c) {
    float4 v = *(const float4*)(frow + (lane8 + 8 * c) * 4);
    va[c] = v;
    sum   += (v.x + v.y) + (v.z + v.w);
    sumsq += (v.x * v.x + v.y * v.y) + (v.z * v.z + v.w * v.w);
  }
#pragma unroll
  for (int off = 1; off < 8; off <<= 1) {
    sum   += __shfl_xor(sum, off);
    sumsq += __shfl_xor(sumsq, off);
  }
  float mean = sum * (1.f / CIN);
  float var  = sumsq * (1.f / CIN) - mean * mean;
  if (var < 0.f) var = 0.f;
  float rs = rsqrtf(var + LN_EPS);
#pragma unroll
  for (int c = 0; c < 12; ++c) {
    float4 g4 = *(const float4*)(ln_g + (lane8 + 8 * c) * 4);
    float4 b4 = *(const float4*)(ln_b + (lane8 + 8 * c) * 4);
    va[c].x = (va[c].x - mean) * rs * g4.x + b4.x;
    va[c].y = (va[c].y - mean) * rs * g4.y + b4.y;
    va[c].z = (va[c].z - mean) * rs * g4.z + b4.z;
    va[c].w = (va[c].w - mean) * rs * g4.w + b4.w;
  }

  // ---- Phase 2: K-chunked GEMM ----
  __shared__ float At[32][36];    // [k in chunk][row], padded
  __shared__ float Bs[32][192];   // [k in chunk][col]
  float acc[4][6];
#pragma unroll
  for (int r = 0; r < 4; ++r)
#pragma unroll
    for (int c = 0; c < 6; ++c) acc[r][c] = 0.f;

  for (int ch = 0; ch < 12; ++ch) {
    if (ch) __syncthreads();
    // stage A chunk (normalized values, transposed)
    At[4 * lane8 + 0][row] = va[ch].x;
    At[4 * lane8 + 1][row] = va[ch].y;
    At[4 * lane8 + 2][row] = va[ch].z;
    At[4 * lane8 + 3][row] = va[ch].w;
    // stage B chunk: w2 rows [32*ch, 32*ch+32)
    const float4* bsrc = (const float4*)(w2 + (size_t)ch * 32 * COUT);
    float4* bdst = (float4*)&Bs[0][0];
#pragma unroll
    for (int s = 0; s < 6; ++s) bdst[tid + 256 * s] = bsrc[tid + 256 * s];
    __syncthreads();
#pragma unroll 4
    for (int kk = 0; kk < 32; ++kk) {
      float4 a = *(const float4*)&At[kk][4 * tr];
      const float* brow = &Bs[kk][6 * tc];
      float2 p0 = *(const float2*)(brow);
      float2 p1 = *(const float2*)(brow + 2);
      float2 p2 = *(const float2*)(brow + 4);
      float ar[4] = {a.x, a.y, a.z, a.w};
      float br[6] = {p0.x, p0.y, p1.x, p1.y, p2.x, p2.y};
#pragma unroll
      for (int r = 0; r < 4; ++r)
#pragma unroll
        for (int c = 0; c < 6; ++c) acc[r][c] = fmaf(ar[r], br[c], acc[r][c]);
    }
  }

  // ---- Epilogue ----
  float bias[6];
#pragma unroll
  for (int c = 0; c < 6; ++c) bias[c] = b2[6 * tc + c];
#pragma unroll
  for (int r = 0; r < 4; ++r) {
    float* orow = h + (size_t)(row_g0 + 4 * tr + r) * COUT + 6 * tc;
#pragma unroll
    for (int c = 0; c < 6; ++c) orow[c] = acc[r][c] + bias[c];
  }
}

// ---------------------------------------------------------------------------
// K2: 3-NN search. One thread per fine (dst) point; coarse (src) xyz in LDS.
// Distance arithmetic replicates the reference f32 rounding exactly
// (no FMA contraction); strict < keeps stable (lower-index) tie-break.
// ---------------------------------------------------------------------------
__global__ __launch_bounds__(256) void k2_knn(
    const float* __restrict__ xyz, const float* __restrict__ sxyz,
    int* __restrict__ knn_i, float* __restrict__ knn_w)
{
  __shared__ float sx[N_C], sy[N_C], sz[N_C];
  const int tid = threadIdx.x;
  const int b   = blockIdx.x >> 6;   // 64 blocks per batch
  const float* src = xyz + (size_t)b * N_C * 3;
#pragma unroll
  for (int s = 0; s < 16; ++s) {
    int j = tid + 256 * s;
    sx[j] = src[j * 3 + 0];
    sy[j] = src[j * 3 + 1];
    sz[j] = src[j * 3 + 2];
  }
  const int dst = blockIdx.x * 256 + tid;   // global fine index
  float px = sxyz[(size_t)dst * 3 + 0];
  float py = sxyz[(size_t)dst * 3 + 1];
  float pz = sxyz[(size_t)dst * 3 + 2];
  __syncthreads();

  float t0 = 1e30f, t1 = 1e30f, t2 = 1e30f;
  int   j0 = 0, j1 = 0, j2 = 0;
#pragma unroll 4
  for (int j = 0; j < N_C; ++j) {
    float dx = __fsub_rn(px, sx[j]);
    float dy = __fsub_rn(py, sy[j]);
    float dz = __fsub_rn(pz, sz[j]);
    float d2 = __fadd_rn(__fadd_rn(__fmul_rn(dx, dx), __fmul_rn(dy, dy)),
                         __fmul_rn(dz, dz));
    if (d2 < t2) {
      if (d2 < t1) {
        t2 = t1; j2 = j1;
        if (d2 < t0) { t1 = t0; j1 = j0; t0 = d2; j0 = j; }
        else         { t1 = d2; j1 = j; }
      } else { t2 = d2; j2 = j; }
    }
  }
  float d0 = sqrtf(t0), d1 = sqrtf(t1), d2s = sqrtf(t2);
  float r0 = 1.f / (d0 + 1e-8f);
  float r1 = 1.f / (d1 + 1e-8f);
  float r2 = 1.f / (d2s + 1e-8f);
  float inv = 1.f / (r0 + r1 + r2);
  knn_i[(size_t)dst * 3 + 0] = b * N_C + j0;
  knn_i[(size_t)dst * 3 + 1] = b * N_C + j1;
  knn_i[(size_t)dst * 3 + 2] = b * N_C + j2;
  knn_w[(size_t)dst * 3 + 0] = r0 * inv;
  knn_w[(size_t)dst * 3 + 1] = r1 * inv;
  knn_w[(size_t)dst * 3 + 2] = r2 * inv;
}

// ---------------------------------------------------------------------------
// K3: out = LN(support_feats) @ w1 + b1 + interp(h)   [65536 x 192]
// Same GEMM structure as K1 (K=192 -> 6 chunks); 3-NN gather fused in epilogue.
// ---------------------------------------------------------------------------
__global__ __launch_bounds__(256) void k3_ln_gemm_interp(
    const float* __restrict__ sfeats, const float* __restrict__ ln_g,
    const float* __restrict__ ln_b, const float* __restrict__ w1,
    const float* __restrict__ b1, const float* __restrict__ h,
    const int* __restrict__ knn_i, const float* __restrict__ knn_w,
    float* __restrict__ out)
{
  const int tid   = threadIdx.x;
  const int row   = tid >> 3;
  const int lane8 = tid & 7;
  const int tr    = tid >> 5;
  const int tc    = tid & 31;
  const int row_g0 = blockIdx.x * 32;

  float4 va[6];
  const float* frow = sfeats + (size_t)(row_g0 + row) * COUT;
  float sum = 0.f, sumsq = 0.f;
#pragma unroll
  for (int c = 0; c < 6; ++c) {
    float4 v = *(const float4*)(frow + (lane8 + 8 * c) * 4);
    va[c] = v;
    sum   += (v.x + v.y) + (v.z + v.w);
    sumsq += (v.x * v.x + v.y * v.y) + (v.z * v.z + v.w * v.w);
  }
#pragma unroll
  for (int off = 1; off < 8; off <<= 1) {
    sum   += __shfl_xor(sum, off);
    sumsq += __shfl_xor(sumsq, off);
  }
  float mean = sum * (1.f / COUT);
  float var  = sumsq * (1.f / COUT) - mean * mean;
  if (var < 0.f) var = 0.f;
  float rs = rsqrtf(var + LN_EPS);
#pragma unroll
  for (int c = 0; c < 6; ++c) {
    float4 g4 = *(const float4*)(ln_g + (lane8 + 8 * c) * 4);
    float4 b4 = *(const float4*)(ln_b + (lane8 + 8 * c) * 4);
    va[c].x = (va[c].x - mean) * rs * g4.x + b4.x;
    va[c].y = (va[c].y - mean) * rs * g4.y + b4.y;
    va[c].z = (va[c].z - mean) * rs * g4.z + b4.z;
    va[c].w = (va[c].w - mean) * rs * g4.w + b4.w;
  }

  __shared__ float At[32][36];
  __shared__ float Bs[32][192];
  float acc[4][6];
#pragma unroll
  for (int r = 0; r < 4; ++r)
#pragma unroll
    for (int c = 0; c < 6; ++c) acc[r][c] = 0.f;

  for (int ch = 0; ch < 6; ++ch) {
    if (ch) __syncthreads();
    At[4 * lane8 + 0][row] = va[ch].x;
    At[4 * lane8 + 1][row] = va[ch].y;
    At[4 * lane8 + 2][row] = va[ch].z;
    At[4 * lane8 + 3][row] = va[ch].w;
    const float4* bsrc = (const float4*)(w1 + (size_t)ch * 32 * COUT);
    float4* bdst = (float4*)&Bs[0][0];
#pragma unroll
    for (int s = 0; s < 6; ++s) bdst[tid + 256 * s] = bsrc[tid + 256 * s];
    __syncthreads();
#pragma unroll 4
    for (int kk = 0; kk < 32; ++kk) {
      float4 a = *(const float4*)&At[kk][4 * tr];
      const float* brow = &Bs[kk][6 * tc];
      float2 p0 = *(const float2*)(brow);
      float2 p1 = *(const float2*)(brow + 2);
      float2 p2 = *(const float2*)(brow + 4);
      float ar[4] = {a.x, a.y, a.z, a.w};
      float br[6] = {p0.x, p0.y, p1.x, p1.y, p2.x, p2.y};
#pragma unroll
      for (int r = 0; r < 4; ++r)
#pragma unroll
        for (int c = 0; c < 6; ++c) acc[r][c] = fmaf(ar[r], br[c], acc[r][c]);
    }
  }

  float bias[6];
#pragma unroll
  for (int c = 0; c < 6; ++c) bias[c] = b1[6 * tc + c];
#pragma unroll
  for (int r = 0; r < 4; ++r) {
    const int dst = row_g0 + 4 * tr + r;
    int   i0 = knn_i[(size_t)dst * 3 + 0];
    int   i1 = knn_i[(size_t)dst * 3 + 1];
    int   i2 = knn_i[(size_t)dst * 3 + 2];
    float w0 = knn_w[(size_t)dst * 3 + 0];
    float w1v = knn_w[(size_t)dst * 3 + 1];
    float w2v = knn_w[(size_t)dst * 3 + 2];
    const float* h0 = h + (size_t)i0 * COUT + 6 * tc;
    const float* h1 = h + (size_t)i1 * COUT + 6 * tc;
    const float* h2 = h + (size_t)i2 * COUT + 6 * tc;
    float* orow = out + (size_t)dst * COUT + 6 * tc;
#pragma unroll
    for (int c = 0; c < 6; ++c)
      orow[c] = acc[r][c] + bias[c] + w0 * h0[c] + w1v * h1[c] + w2v * h2[c];
  }
}

// ---------------------------------------------------------------------------
// K4: passthrough outputs — support_xyz copy + support_offset as float
// ---------------------------------------------------------------------------
__global__ __launch_bounds__(256) void k4_tail(
    const float* __restrict__ sxyz, const int* __restrict__ soff,
    float* __restrict__ out_tail)
{
  const int t = blockIdx.x * 256 + threadIdx.x;
  if (t < MF * 3) out_tail[t] = sxyz[t];
  if (t < B_SEG) out_tail[MF * 3 + t] = (float)soff[t];
}

// ---------------------------------------------------------------------------
extern "C" void kernel_launch(void* const* d_in, const int* in_sizes, int n_in,
                              void* d_out, int out_size, void* d_ws, size_t ws_size,
                              hipStream_t stream)
{
  const float* feats  = (const float*)d_in[0];
  const float* xyz    = (const float*)d_in[1];
  const float* sxyz   = (const float*)d_in[2];
  const float* sfeats = (const float*)d_in[3];
  const int*   soff   = (const int*)d_in[5];
  const float* ln1_g  = (const float*)d_in[6];
  const float* ln1_b  = (const float*)d_in[7];
  const float* w1     = (const float*)d_in[8];
  const float* b1     = (const float*)d_in[9];
  const float* ln2_g  = (const float*)d_in[10];
  const float* ln2_b  = (const float*)d_in[11];
  const float* w2     = (const float*)d_in[12];
  const float* b2     = (const float*)d_in[13];
  float* out = (float*)d_out;

  // workspace layout
  float* h     = (float*)d_ws;                    // 16384*192 floats
  int*   knn_i = (int*)(h + (size_t)MT * COUT);   // 65536*3 ints
  float* knn_w = (float*)(knn_i + (size_t)MF * 3);// 65536*3 floats

  k1_ln_gemm<<<MT / 32, 256, 0, stream>>>(feats, ln2_g, ln2_b, w2, b2, h);
  k2_knn<<<MF / 256, 256, 0, stream>>>(xyz, sxyz, knn_i, knn_w);
  k3_ln_gemm_interp<<<MF / 32, 256, 0, stream>>>(sfeats, ln1_g, ln1_b, w1, b1,
                                                 h, knn_i, knn_w, out);
  k4_tail<<<(MF * 3) / 256, 256, 0, stream>>>(sxyz, soff, out + (size_t)MF * COUT);
}

// Round 2
// 394.151 us; speedup vs baseline: 1.5890x; 1.5890x over previous
//
#include <hip/hip_runtime.h>
#include <cstddef>
#include <cstdint>

// Problem constants (fixed by setup_inputs)
constexpr int B_SEG   = 4;
constexpr int N_C     = 4096;    // coarse points per batch
constexpr int M_F     = 16384;   // fine points per batch
constexpr int CIN     = 384;
constexpr int COUT    = 192;
constexpr int MT      = B_SEG * N_C;   // 16384 coarse rows
constexpr int MF      = B_SEG * M_F;   // 65536 fine rows
constexpr float LN_EPS = 1e-5f;

constexpr int NSEG    = 4;             // src-scan segments for KNN
constexpr int SEGLEN  = N_C / NSEG;    // 1024 src points per segment

// ---------------------------------------------------------------------------
// K1: h = LN(feats) @ w2 + b2      [16384 x 384] -> [16384 x 192]
// ---------------------------------------------------------------------------
__global__ __launch_bounds__(256) void k1_ln_gemm(
    const float* __restrict__ feats, const float* __restrict__ ln_g,
    const float* __restrict__ ln_b, const float* __restrict__ w2,
    const float* __restrict__ b2, float* __restrict__ h)
{
  const int tid   = threadIdx.x;
  const int row   = tid >> 3;   // 0..31 (LN role)
  const int lane8 = tid & 7;    // 0..7
  const int tr    = tid >> 5;   // 0..7  (GEMM role: 4 rows each)
  const int tc    = tid & 31;   // 0..31 (6 cols each)
  const int row_g0 = blockIdx.x * 32;

  float4 va[12];
  const float* frow = feats + (size_t)(row_g0 + row) * CIN;
  float sum = 0.f, sumsq = 0.f;
#pragma unroll
  for (int c = 0; c < 12; ++c) {
    float4 v = *(const float4*)(frow + (lane8 + 8 * c) * 4);
    va[c] = v;
    sum   += (v.x + v.y) + (v.z + v.w);
    sumsq += (v.x * v.x + v.y * v.y) + (v.z * v.z + v.w * v.w);
  }
#pragma unroll
  for (int off = 1; off < 8; off <<= 1) {
    sum   += __shfl_xor(sum, off);
    sumsq += __shfl_xor(sumsq, off);
  }
  float mean = sum * (1.f / CIN);
  float var  = sumsq * (1.f / CIN) - mean * mean;
  if (var < 0.f) var = 0.f;
  float rs = rsqrtf(var + LN_EPS);
#pragma unroll
  for (int c = 0; c < 12; ++c) {
    float4 g4 = *(const float4*)(ln_g + (lane8 + 8 * c) * 4);
    float4 b4 = *(const float4*)(ln_b + (lane8 + 8 * c) * 4);
    va[c].x = (va[c].x - mean) * rs * g4.x + b4.x;
    va[c].y = (va[c].y - mean) * rs * g4.y + b4.y;
    va[c].z = (va[c].z - mean) * rs * g4.z + b4.z;
    va[c].w = (va[c].w - mean) * rs * g4.w + b4.w;
  }

  __shared__ float At[32][36];
  __shared__ float Bs[32][192];
  float acc[4][6];
#pragma unroll
  for (int r = 0; r < 4; ++r)
#pragma unroll
    for (int c = 0; c < 6; ++c) acc[r][c] = 0.f;

  for (int ch = 0; ch < 12; ++ch) {
    if (ch) __syncthreads();
    At[4 * lane8 + 0][row] = va[ch].x;
    At[4 * lane8 + 1][row] = va[ch].y;
    At[4 * lane8 + 2][row] = va[ch].z;
    At[4 * lane8 + 3][row] = va[ch].w;
    const float4* bsrc = (const float4*)(w2 + (size_t)ch * 32 * COUT);
    float4* bdst = (float4*)&Bs[0][0];
#pragma unroll
    for (int s = 0; s < 6; ++s) bdst[tid + 256 * s] = bsrc[tid + 256 * s];
    __syncthreads();
#pragma unroll 4
    for (int kk = 0; kk < 32; ++kk) {
      float4 a = *(const float4*)&At[kk][4 * tr];
      const float* brow = &Bs[kk][6 * tc];
      float2 p0 = *(const float2*)(brow);
      float2 p1 = *(const float2*)(brow + 2);
      float2 p2 = *(const float2*)(brow + 4);
      float ar[4] = {a.x, a.y, a.z, a.w};
      float br[6] = {p0.x, p0.y, p1.x, p1.y, p2.x, p2.y};
#pragma unroll
      for (int r = 0; r < 4; ++r)
#pragma unroll
        for (int c = 0; c < 6; ++c) acc[r][c] = fmaf(ar[r], br[c], acc[r][c]);
    }
  }

  float bias[6];
#pragma unroll
  for (int c = 0; c < 6; ++c) bias[c] = b2[6 * tc + c];
#pragma unroll
  for (int r = 0; r < 4; ++r) {
    float* orow = h + (size_t)(row_g0 + 4 * tr + r) * COUT + 6 * tc;
#pragma unroll
    for (int c = 0; c < 6; ++c) orow[c] = acc[r][c] + bias[c];
  }
}

// ---------------------------------------------------------------------------
// K2a: partial 3-NN over one src segment (SEGLEN points) per block.
// Grid = (MF/256) * NSEG -> 1024 blocks -> ~16 waves/CU.
// Partial lists are sorted lexicographically by (d2, j): strict-< insert
// with increasing j preserves the stable (lower-index-first) order.
// Distance arithmetic replicates reference f32 rounding (no FMA contraction).
// Partial layout: pd2[dst*16 + seg*4 + k] (k=3 pad 1e30), pj same.
// ---------------------------------------------------------------------------
__global__ __launch_bounds__(256) void k2a_knn_part(
    const float* __restrict__ xyz, const float* __restrict__ sxyz,
    float* __restrict__ pd2, int* __restrict__ pj)
{
  __shared__ float lds[SEGLEN * 3];
  const int tid = threadIdx.x;
  const int dgrp = blockIdx.x >> 2;        // dst group (0..255)
  const int seg  = blockIdx.x & 3;         // src segment (0..3)
  const int b    = dgrp >> 6;              // batch (64 dst groups per batch)
  const float* src = xyz + ((size_t)b * N_C + (size_t)seg * SEGLEN) * 3;
  // stage segment (3072 floats = 768 float4), perfectly coalesced
  {
    const float4* s4 = (const float4*)src;
    float4* d4 = (float4*)lds;
#pragma unroll
    for (int i = 0; i < 3; ++i) d4[tid + 256 * i] = s4[tid + 256 * i];
  }
  const int dst = dgrp * 256 + tid;        // global fine index
  float px = sxyz[(size_t)dst * 3 + 0];
  float py = sxyz[(size_t)dst * 3 + 1];
  float pz = sxyz[(size_t)dst * 3 + 2];
  __syncthreads();

  float t0 = 1e30f, t1 = 1e30f, t2 = 1e30f;
  int   j0 = -1, j1 = -1, j2 = -1;
#pragma unroll 8
  for (int j = 0; j < SEGLEN; ++j) {
    float dx = __fsub_rn(px, lds[3 * j + 0]);
    float dy = __fsub_rn(py, lds[3 * j + 1]);
    float dz = __fsub_rn(pz, lds[3 * j + 2]);
    float d2 = __fadd_rn(__fadd_rn(__fmul_rn(dx, dx), __fmul_rn(dy, dy)),
                         __fmul_rn(dz, dz));
    if (d2 < t2) {
      if (d2 < t1) {
        t2 = t1; j2 = j1;
        if (d2 < t0) { t1 = t0; j1 = j0; t0 = d2; j0 = j; }
        else         { t1 = d2; j1 = j; }
      } else { t2 = d2; j2 = j; }
    }
  }
  const int jb = b * N_C + seg * SEGLEN;   // global row base for this segment
  const size_t o = (size_t)dst * 16 + seg * 4;
  *(float4*)(pd2 + o) = make_float4(t0, t1, t2, 1e30f);
  *(int4*)(pj + o)    = make_int4(jb + j0, jb + j1, jb + j2, 0x7fffffff);
}

// ---------------------------------------------------------------------------
// K2b: merge NSEG partial top-3 lists -> final top-3 + inverse-distance weights.
// Lexicographic (d2, idx) insert == stable top_k tie-break.
// ---------------------------------------------------------------------------
__global__ __launch_bounds__(256) void k2b_knn_merge(
    const float* __restrict__ pd2, const int* __restrict__ pj,
    int* __restrict__ knn_i, float* __restrict__ knn_w)
{
  const int dst = blockIdx.x * 256 + threadIdx.x;
  const size_t base = (size_t)dst * 16;
  float t0 = 1e30f, t1 = 1e30f, t2 = 1e30f;
  int   j0 = 0x7fffffff, j1 = 0x7fffffff, j2 = 0x7fffffff;
#pragma unroll
  for (int s = 0; s < 4; ++s) {
    float4 d4 = *(const float4*)(pd2 + base + s * 4);
    int4   i4 = *(const int4*)(pj + base + s * 4);
    float dc[4] = {d4.x, d4.y, d4.z, d4.w};
    int   ic[4] = {i4.x, i4.y, i4.z, i4.w};
#pragma unroll
    for (int k = 0; k < 4; ++k) {
      float d = dc[k]; int j = ic[k];
      bool lt2 = (d < t2) || (d == t2 && j < j2);
      if (lt2) {
        bool lt1 = (d < t1) || (d == t1 && j < j1);
        if (lt1) {
          t2 = t1; j2 = j1;
          bool lt0 = (d < t0) || (d == t0 && j < j0);
          if (lt0) { t1 = t0; j1 = j0; t0 = d; j0 = j; }
          else     { t1 = d; j1 = j; }
        } else { t2 = d; j2 = j; }
      }
    }
  }
  float d0 = sqrtf(t0), d1 = sqrtf(t1), d2s = sqrtf(t2);
  float r0 = 1.f / (d0 + 1e-8f);
  float r1 = 1.f / (d1 + 1e-8f);
  float r2 = 1.f / (d2s + 1e-8f);
  float inv = 1.f / (r0 + r1 + r2);
  knn_i[(size_t)dst * 3 + 0] = j0;
  knn_i[(size_t)dst * 3 + 1] = j1;
  knn_i[(size_t)dst * 3 + 2] = j2;
  knn_w[(size_t)dst * 3 + 0] = r0 * inv;
  knn_w[(size_t)dst * 3 + 1] = r1 * inv;
  knn_w[(size_t)dst * 3 + 2] = r2 * inv;
}

// ---------------------------------------------------------------------------
// K3: out = LN(support_feats) @ w1 + b1 + interp(h)   [65536 x 192]
// ---------------------------------------------------------------------------
__global__ __launch_bounds__(256) void k3_ln_gemm_interp(
    const float* __restrict__ sfeats, const float* __restrict__ ln_g,
    const float* __restrict__ ln_b, const float* __restrict__ w1,
    const float* __restrict__ b1, const float* __restrict__ h,
    const int* __restrict__ knn_i, const float* __restrict__ knn_w,
    float* __restrict__ out)
{
  const int tid   = threadIdx.x;
  const int row   = tid >> 3;
  const int lane8 = tid & 7;
  const int tr    = tid >> 5;
  const int tc    = tid & 31;
  const int row_g0 = blockIdx.x * 32;

  float4 va[6];
  const float* frow = sfeats + (size_t)(row_g0 + row) * COUT;
  float sum = 0.f, sumsq = 0.f;
#pragma unroll
  for (int c = 0; c < 6; ++c) {
    float4 v = *(const float4*)(frow + (lane8 + 8 * c) * 4);
    va[c] = v;
    sum   += (v.x + v.y) + (v.z + v.w);
    sumsq += (v.x * v.x + v.y * v.y) + (v.z * v.z + v.w * v.w);
  }
#pragma unroll
  for (int off = 1; off < 8; off <<= 1) {
    sum   += __shfl_xor(sum, off);
    sumsq += __shfl_xor(sumsq, off);
  }
  float mean = sum * (1.f / COUT);
  float var  = sumsq * (1.f / COUT) - mean * mean;
  if (var < 0.f) var = 0.f;
  float rs = rsqrtf(var + LN_EPS);
#pragma unroll
  for (int c = 0; c < 6; ++c) {
    float4 g4 = *(const float4*)(ln_g + (lane8 + 8 * c) * 4);
    float4 b4 = *(const float4*)(ln_b + (lane8 + 8 * c) * 4);
    va[c].x = (va[c].x - mean) * rs * g4.x + b4.x;
    va[c].y = (va[c].y - mean) * rs * g4.y + b4.y;
    va[c].z = (va[c].z - mean) * rs * g4.z + b4.z;
    va[c].w = (va[c].w - mean) * rs * g4.w + b4.w;
  }

  __shared__ float At[32][36];
  __shared__ float Bs[32][192];
  float acc[4][6];
#pragma unroll
  for (int r = 0; r < 4; ++r)
#pragma unroll
    for (int c = 0; c < 6; ++c) acc[r][c] = 0.f;

  for (int ch = 0; ch < 6; ++ch) {
    if (ch) __syncthreads();
    At[4 * lane8 + 0][row] = va[ch].x;
    At[4 * lane8 + 1][row] = va[ch].y;
    At[4 * lane8 + 2][row] = va[ch].z;
    At[4 * lane8 + 3][row] = va[ch].w;
    const float4* bsrc = (const float4*)(w1 + (size_t)ch * 32 * COUT);
    float4* bdst = (float4*)&Bs[0][0];
#pragma unroll
    for (int s = 0; s < 6; ++s) bdst[tid + 256 * s] = bsrc[tid + 256 * s];
    __syncthreads();
#pragma unroll 4
    for (int kk = 0; kk < 32; ++kk) {
      float4 a = *(const float4*)&At[kk][4 * tr];
      const float* brow = &Bs[kk][6 * tc];
      float2 p0 = *(const float2*)(brow);
      float2 p1 = *(const float2*)(brow + 2);
      float2 p2 = *(const float2*)(brow + 4);
      float ar[4] = {a.x, a.y, a.z, a.w};
      float br[6] = {p0.x, p0.y, p1.x, p1.y, p2.x, p2.y};
#pragma unroll
      for (int r = 0; r < 4; ++r)
#pragma unroll
        for (int c = 0; c < 6; ++c) acc[r][c] = fmaf(ar[r], br[c], acc[r][c]);
    }
  }

  float bias[6];
#pragma unroll
  for (int c = 0; c < 6; ++c) bias[c] = b1[6 * tc + c];
#pragma unroll
  for (int r = 0; r < 4; ++r) {
    const int dst = row_g0 + 4 * tr + r;
    int   i0 = knn_i[(size_t)dst * 3 + 0];
    int   i1 = knn_i[(size_t)dst * 3 + 1];
    int   i2 = knn_i[(size_t)dst * 3 + 2];
    float w0 = knn_w[(size_t)dst * 3 + 0];
    float w1v = knn_w[(size_t)dst * 3 + 1];
    float w2v = knn_w[(size_t)dst * 3 + 2];
    const float* h0 = h + (size_t)i0 * COUT + 6 * tc;
    const float* h1 = h + (size_t)i1 * COUT + 6 * tc;
    const float* h2 = h + (size_t)i2 * COUT + 6 * tc;
    float* orow = out + (size_t)dst * COUT + 6 * tc;
#pragma unroll
    for (int c = 0; c < 6; ++c)
      orow[c] = acc[r][c] + bias[c] + w0 * h0[c] + w1v * h1[c] + w2v * h2[c];
  }
}

// ---------------------------------------------------------------------------
// K4: passthrough outputs — support_xyz copy + support_offset as float
// ---------------------------------------------------------------------------
__global__ __launch_bounds__(256) void k4_tail(
    const float* __restrict__ sxyz, const int* __restrict__ soff,
    float* __restrict__ out_tail)
{
  const int t = blockIdx.x * 256 + threadIdx.x;
  if (t < MF * 3) out_tail[t] = sxyz[t];
  if (t < B_SEG) out_tail[MF * 3 + t] = (float)soff[t];
}

// ---------------------------------------------------------------------------
extern "C" void kernel_launch(void* const* d_in, const int* in_sizes, int n_in,
                              void* d_out, int out_size, void* d_ws, size_t ws_size,
                              hipStream_t stream)
{
  const float* feats  = (const float*)d_in[0];
  const float* xyz    = (const float*)d_in[1];
  const float* sxyz   = (const float*)d_in[2];
  const float* sfeats = (const float*)d_in[3];
  const int*   soff   = (const int*)d_in[5];
  const float* ln1_g  = (const float*)d_in[6];
  const float* ln1_b  = (const float*)d_in[7];
  const float* w1     = (const float*)d_in[8];
  const float* b1     = (const float*)d_in[9];
  const float* ln2_g  = (const float*)d_in[10];
  const float* ln2_b  = (const float*)d_in[11];
  const float* w2     = (const float*)d_in[12];
  const float* b2     = (const float*)d_in[13];
  float* out = (float*)d_out;

  // workspace layout
  float* h     = (float*)d_ws;                      // 16384*192 floats (12.6 MB)
  int*   knn_i = (int*)(h + (size_t)MT * COUT);     // 65536*3 ints
  float* knn_w = (float*)(knn_i + (size_t)MF * 3);  // 65536*3 floats
  float* pd2   = knn_w + (size_t)MF * 3;            // 65536*16 floats (4 MB)
  int*   pj    = (int*)(pd2 + (size_t)MF * 16);     // 65536*16 ints   (4 MB)

  k1_ln_gemm<<<MT / 32, 256, 0, stream>>>(feats, ln2_g, ln2_b, w2, b2, h);
  k2a_knn_part<<<(MF / 256) * NSEG, 256, 0, stream>>>(xyz, sxyz, pd2, pj);
  k2b_knn_merge<<<MF / 256, 256, 0, stream>>>(pd2, pj, knn_i, knn_w);
  k3_ln_gemm_interp<<<MF / 32, 256, 0, stream>>>(sfeats, ln1_g, ln1_b, w1, b1,
                                                 h, knn_i, knn_w, out);
  k4_tail<<<(MF * 3) / 256, 256, 0, stream>>>(sxyz, soff, out + (size_t)MF * COUT);
}

// Round 3
// 344.696 us; speedup vs baseline: 1.8170x; 1.1435x over previous
//
#include <hip/hip_runtime.h>
#include <cstddef>
#include <cstdint>

// Problem constants (fixed by setup_inputs)
constexpr int B_SEG   = 4;
constexpr int N_C     = 4096;    // coarse points per batch
constexpr int M_F     = 16384;   // fine points per batch
constexpr int CIN     = 384;
constexpr int COUT    = 192;
constexpr int MT      = B_SEG * N_C;   // 16384 coarse rows
constexpr int MF      = B_SEG * M_F;   // 65536 fine rows
constexpr float LN_EPS = 1e-5f;

constexpr int NSEG    = 4;             // src-scan segments for KNN
constexpr int SEGLEN  = N_C / NSEG;    // 1024 src points per segment

typedef __bf16 bf16x8 __attribute__((ext_vector_type(8)));
typedef __bf16 bf16x4 __attribute__((ext_vector_type(4)));
typedef float  f32x4  __attribute__((ext_vector_type(4)));

// ---------------------------------------------------------------------------
// K0: one-time prep — transpose+convert weights to bf16 [n][k] layout so the
// GEMM kernels load B-fragments as contiguous 16B global reads.
// ---------------------------------------------------------------------------
__global__ __launch_bounds__(256) void k0_prep(
    const float* __restrict__ w2, const float* __restrict__ w1,
    __bf16* __restrict__ wt2, __bf16* __restrict__ wt1)
{
  int e = blockIdx.x * 256 + threadIdx.x;
  if (e < CIN * COUT) {                       // w2: [384][192] -> wt2 [192][384]
    int k = e / COUT, n = e % COUT;
    wt2[(size_t)n * CIN + k] = (__bf16)w2[e];
  }
  e -= CIN * COUT;
  if (e >= 0 && e < COUT * COUT) {            // w1: [192][192] -> wt1 [192][192]
    int k = e / COUT, n = e % COUT;
    wt1[(size_t)n * COUT + k] = (__bf16)w1[e];
  }
}

// ---------------------------------------------------------------------------
// K1: h = LN(feats) @ w2 + b2      [16384 x 384] x [384 x 192]
// Block: 256 thr = 4 waves, 64 rows. LN in registers -> bf16 A-tile in LDS
// (MFMA A-layout, rows padded +8 bf16 => 2-way bank alias, free).
// B-frags: direct global bf16x8 loads from pre-transposed wt2 (L1-hot).
// One __syncthreads total; K-loop has no barriers.
// ---------------------------------------------------------------------------
__global__ __launch_bounds__(256) void k1_ln_gemm(
    const float* __restrict__ feats, const float* __restrict__ ln_g,
    const float* __restrict__ ln_b, const __bf16* __restrict__ wt2,
    const float* __restrict__ b2, float* __restrict__ h)
{
  __shared__ __bf16 As[64][CIN + 8];
  const int tid = threadIdx.x;
  const int blk = blockIdx.x;

  // ---- Phase 1: LN (4 threads/row, 24 float4 each) ----
  {
    const int r = tid >> 2, q = tid & 3;
    const float* frow = feats + (size_t)(blk * 64 + r) * CIN;
    float4 v[24];
    float sum = 0.f, sumsq = 0.f;
#pragma unroll
    for (int i = 0; i < 24; ++i) {
      float4 t = *(const float4*)(frow + (q + 4 * i) * 4);
      v[i] = t;
      sum   += (t.x + t.y) + (t.z + t.w);
      sumsq += (t.x * t.x + t.y * t.y) + (t.z * t.z + t.w * t.w);
    }
    sum   += __shfl_xor(sum, 1);  sumsq += __shfl_xor(sumsq, 1);
    sum   += __shfl_xor(sum, 2);  sumsq += __shfl_xor(sumsq, 2);
    float mean = sum * (1.f / CIN);
    float var  = sumsq * (1.f / CIN) - mean * mean;
    if (var < 0.f) var = 0.f;
    float rs = rsqrtf(var + LN_EPS);
#pragma unroll
    for (int i = 0; i < 24; ++i) {
      float4 g4 = *(const float4*)(ln_g + (q + 4 * i) * 4);
      float4 b4 = *(const float4*)(ln_b + (q + 4 * i) * 4);
      bf16x4 o;
      o[0] = (__bf16)((v[i].x - mean) * rs * g4.x + b4.x);
      o[1] = (__bf16)((v[i].y - mean) * rs * g4.y + b4.y);
      o[2] = (__bf16)((v[i].z - mean) * rs * g4.z + b4.z);
      o[3] = (__bf16)((v[i].w - mean) * rs * g4.w + b4.w);
      *(bf16x4*)&As[r][(q + 4 * i) * 4] = o;
    }
  }
  __syncthreads();

  // ---- Phase 2: MFMA ----
  const int w = tid >> 6, lane = tid & 63, m = lane & 15, half = lane >> 4;
  f32x4 acc[12];
#pragma unroll
  for (int t = 0; t < 12; ++t) acc[t] = (f32x4){0.f, 0.f, 0.f, 0.f};

  const __bf16* Arow = &As[16 * w + m][half * 8];
  const __bf16* Bbase = wt2 + (size_t)m * CIN + half * 8;
#pragma unroll
  for (int ch = 0; ch < 12; ++ch) {
    bf16x8 a = *(const bf16x8*)(Arow + ch * 32);
#pragma unroll
    for (int t = 0; t < 12; ++t) {
      bf16x8 b = *(const bf16x8*)(Bbase + (size_t)(16 * t) * CIN + ch * 32);
      acc[t] = __builtin_amdgcn_mfma_f32_16x16x32_bf16(a, b, acc[t], 0, 0, 0);
    }
  }

  // ---- Epilogue: D layout col=lane&15, row=(lane>>4)*4+reg ----
  const int r0 = blk * 64 + 16 * w + half * 4;
#pragma unroll
  for (int t = 0; t < 12; ++t) {
    float bv = b2[16 * t + m];
#pragma unroll
    for (int reg = 0; reg < 4; ++reg)
      h[(size_t)(r0 + reg) * COUT + 16 * t + m] = acc[t][reg] + bv;
  }
}

// ---------------------------------------------------------------------------
// K2a: partial 3-NN over one src segment per block (unchanged from R2).
// ---------------------------------------------------------------------------
__global__ __launch_bounds__(256) void k2a_knn_part(
    const float* __restrict__ xyz, const float* __restrict__ sxyz,
    float* __restrict__ pd2, int* __restrict__ pj)
{
  __shared__ float lds[SEGLEN * 3];
  const int tid = threadIdx.x;
  const int dgrp = blockIdx.x >> 2;
  const int seg  = blockIdx.x & 3;
  const int b    = dgrp >> 6;
  const float* src = xyz + ((size_t)b * N_C + (size_t)seg * SEGLEN) * 3;
  {
    const float4* s4 = (const float4*)src;
    float4* d4 = (float4*)lds;
#pragma unroll
    for (int i = 0; i < 3; ++i) d4[tid + 256 * i] = s4[tid + 256 * i];
  }
  const int dst = dgrp * 256 + tid;
  float px = sxyz[(size_t)dst * 3 + 0];
  float py = sxyz[(size_t)dst * 3 + 1];
  float pz = sxyz[(size_t)dst * 3 + 2];
  __syncthreads();

  float t0 = 1e30f, t1 = 1e30f, t2 = 1e30f;
  int   j0 = -1, j1 = -1, j2 = -1;
#pragma unroll 8
  for (int j = 0; j < SEGLEN; ++j) {
    float dx = __fsub_rn(px, lds[3 * j + 0]);
    float dy = __fsub_rn(py, lds[3 * j + 1]);
    float dz = __fsub_rn(pz, lds[3 * j + 2]);
    float d2 = __fadd_rn(__fadd_rn(__fmul_rn(dx, dx), __fmul_rn(dy, dy)),
                         __fmul_rn(dz, dz));
    if (d2 < t2) {
      if (d2 < t1) {
        t2 = t1; j2 = j1;
        if (d2 < t0) { t1 = t0; j1 = j0; t0 = d2; j0 = j; }
        else         { t1 = d2; j1 = j; }
      } else { t2 = d2; j2 = j; }
    }
  }
  const int jb = b * N_C + seg * SEGLEN;
  const size_t o = (size_t)dst * 16 + seg * 4;
  *(float4*)(pd2 + o) = make_float4(t0, t1, t2, 1e30f);
  *(int4*)(pj + o)    = make_int4(jb + j0, jb + j1, jb + j2, 0x7fffffff);
}

// ---------------------------------------------------------------------------
// K2b: merge partial lists -> final top-3 + weights (unchanged from R2).
// ---------------------------------------------------------------------------
__global__ __launch_bounds__(256) void k2b_knn_merge(
    const float* __restrict__ pd2, const int* __restrict__ pj,
    int* __restrict__ knn_i, float* __restrict__ knn_w)
{
  const int dst = blockIdx.x * 256 + threadIdx.x;
  const size_t base = (size_t)dst * 16;
  float t0 = 1e30f, t1 = 1e30f, t2 = 1e30f;
  int   j0 = 0x7fffffff, j1 = 0x7fffffff, j2 = 0x7fffffff;
#pragma unroll
  for (int s = 0; s < 4; ++s) {
    float4 d4 = *(const float4*)(pd2 + base + s * 4);
    int4   i4 = *(const int4*)(pj + base + s * 4);
    float dc[4] = {d4.x, d4.y, d4.z, d4.w};
    int   ic[4] = {i4.x, i4.y, i4.z, i4.w};
#pragma unroll
    for (int k = 0; k < 4; ++k) {
      float d = dc[k]; int j = ic[k];
      bool lt2 = (d < t2) || (d == t2 && j < j2);
      if (lt2) {
        bool lt1 = (d < t1) || (d == t1 && j < j1);
        if (lt1) {
          t2 = t1; j2 = j1;
          bool lt0 = (d < t0) || (d == t0 && j < j0);
          if (lt0) { t1 = t0; j1 = j0; t0 = d; j0 = j; }
          else     { t1 = d; j1 = j; }
        } else { t2 = d; j2 = j; }
      }
    }
  }
  float d0 = sqrtf(t0), d1 = sqrtf(t1), d2s = sqrtf(t2);
  float r0 = 1.f / (d0 + 1e-8f);
  float r1 = 1.f / (d1 + 1e-8f);
  float r2 = 1.f / (d2s + 1e-8f);
  float inv = 1.f / (r0 + r1 + r2);
  knn_i[(size_t)dst * 3 + 0] = j0;
  knn_i[(size_t)dst * 3 + 1] = j1;
  knn_i[(size_t)dst * 3 + 2] = j2;
  knn_w[(size_t)dst * 3 + 0] = r0 * inv;
  knn_w[(size_t)dst * 3 + 1] = r1 * inv;
  knn_w[(size_t)dst * 3 + 2] = r2 * inv;
}

// ---------------------------------------------------------------------------
// K3: out = LN(support_feats) @ w1 + b1 + interp(h)   [65536 x 192] x [192 x 192]
// Same MFMA structure as K1 (K=192 -> 6 chunks); 3-NN gather in epilogue.
// ---------------------------------------------------------------------------
__global__ __launch_bounds__(256) void k3_ln_gemm_interp(
    const float* __restrict__ sfeats, const float* __restrict__ ln_g,
    const float* __restrict__ ln_b, const __bf16* __restrict__ wt1,
    const float* __restrict__ b1, const float* __restrict__ h,
    const int* __restrict__ knn_i, const float* __restrict__ knn_w,
    float* __restrict__ out)
{
  __shared__ __bf16 As[64][COUT + 8];
  const int tid = threadIdx.x;
  const int blk = blockIdx.x;

  // ---- Phase 1: LN (4 threads/row, 12 float4 each) ----
  {
    const int r = tid >> 2, q = tid & 3;
    const float* frow = sfeats + (size_t)(blk * 64 + r) * COUT;
    float4 v[12];
    float sum = 0.f, sumsq = 0.f;
#pragma unroll
    for (int i = 0; i < 12; ++i) {
      float4 t = *(const float4*)(frow + (q + 4 * i) * 4);
      v[i] = t;
      sum   += (t.x + t.y) + (t.z + t.w);
      sumsq += (t.x * t.x + t.y * t.y) + (t.z * t.z + t.w * t.w);
    }
    sum   += __shfl_xor(sum, 1);  sumsq += __shfl_xor(sumsq, 1);
    sum   += __shfl_xor(sum, 2);  sumsq += __shfl_xor(sumsq, 2);
    float mean = sum * (1.f / COUT);
    float var  = sumsq * (1.f / COUT) - mean * mean;
    if (var < 0.f) var = 0.f;
    float rs = rsqrtf(var + LN_EPS);
#pragma unroll
    for (int i = 0; i < 12; ++i) {
      float4 g4 = *(const float4*)(ln_g + (q + 4 * i) * 4);
      float4 b4 = *(const float4*)(ln_b + (q + 4 * i) * 4);
      bf16x4 o;
      o[0] = (__bf16)((v[i].x - mean) * rs * g4.x + b4.x);
      o[1] = (__bf16)((v[i].y - mean) * rs * g4.y + b4.y);
      o[2] = (__bf16)((v[i].z - mean) * rs * g4.z + b4.z);
      o[3] = (__bf16)((v[i].w - mean) * rs * g4.w + b4.w);
      *(bf16x4*)&As[r][(q + 4 * i) * 4] = o;
    }
  }
  __syncthreads();

  // ---- Phase 2: MFMA ----
  const int w = tid >> 6, lane = tid & 63, m = lane & 15, half = lane >> 4;
  f32x4 acc[12];
#pragma unroll
  for (int t = 0; t < 12; ++t) acc[t] = (f32x4){0.f, 0.f, 0.f, 0.f};

  const __bf16* Arow = &As[16 * w + m][half * 8];
  const __bf16* Bbase = wt1 + (size_t)m * COUT + half * 8;
#pragma unroll
  for (int ch = 0; ch < 6; ++ch) {
    bf16x8 a = *(const bf16x8*)(Arow + ch * 32);
#pragma unroll
    for (int t = 0; t < 12; ++t) {
      bf16x8 b = *(const bf16x8*)(Bbase + (size_t)(16 * t) * COUT + ch * 32);
      acc[t] = __builtin_amdgcn_mfma_f32_16x16x32_bf16(a, b, acc[t], 0, 0, 0);
    }
  }

  // ---- Epilogue: bias + 3-NN inverse-distance gather from h ----
  float bv[12];
#pragma unroll
  for (int t = 0; t < 12; ++t) bv[t] = b1[16 * t + m];
  const int r0 = blk * 64 + 16 * w + half * 4;
#pragma unroll
  for (int reg = 0; reg < 4; ++reg) {
    const int R = r0 + reg;
    int   i0 = knn_i[(size_t)R * 3 + 0];
    int   i1 = knn_i[(size_t)R * 3 + 1];
    int   i2 = knn_i[(size_t)R * 3 + 2];
    float w0 = knn_w[(size_t)R * 3 + 0];
    float w1v = knn_w[(size_t)R * 3 + 1];
    float w2v = knn_w[(size_t)R * 3 + 2];
    const float* h0 = h + (size_t)i0 * COUT;
    const float* h1 = h + (size_t)i1 * COUT;
    const float* h2 = h + (size_t)i2 * COUT;
    float* orow = out + (size_t)R * COUT;
#pragma unroll
    for (int t = 0; t < 12; ++t) {
      int col = 16 * t + m;
      orow[col] = acc[t][reg] + bv[t] +
                  w0 * h0[col] + w1v * h1[col] + w2v * h2[col];
    }
  }
}

// ---------------------------------------------------------------------------
// K4: passthrough outputs — support_xyz copy + support_offset as float
// ---------------------------------------------------------------------------
__global__ __launch_bounds__(256) void k4_tail(
    const float* __restrict__ sxyz, const int* __restrict__ soff,
    float* __restrict__ out_tail)
{
  const int t = blockIdx.x * 256 + threadIdx.x;
  if (t < MF * 3) out_tail[t] = sxyz[t];
  if (t < B_SEG) out_tail[MF * 3 + t] = (float)soff[t];
}

// ---------------------------------------------------------------------------
extern "C" void kernel_launch(void* const* d_in, const int* in_sizes, int n_in,
                              void* d_out, int out_size, void* d_ws, size_t ws_size,
                              hipStream_t stream)
{
  const float* feats  = (const float*)d_in[0];
  const float* xyz    = (const float*)d_in[1];
  const float* sxyz   = (const float*)d_in[2];
  const float* sfeats = (const float*)d_in[3];
  const int*   soff   = (const int*)d_in[5];
  const float* ln1_g  = (const float*)d_in[6];
  const float* ln1_b  = (const float*)d_in[7];
  const float* w1     = (const float*)d_in[8];
  const float* b1     = (const float*)d_in[9];
  const float* ln2_g  = (const float*)d_in[10];
  const float* ln2_b  = (const float*)d_in[11];
  const float* w2     = (const float*)d_in[12];
  const float* b2     = (const float*)d_in[13];
  float* out = (float*)d_out;

  // workspace layout
  float*  h     = (float*)d_ws;                      // 16384*192 f32 (12.6 MB)
  int*    knn_i = (int*)(h + (size_t)MT * COUT);     // 65536*3 ints
  float*  knn_w = (float*)(knn_i + (size_t)MF * 3);  // 65536*3 floats
  float*  pd2   = knn_w + (size_t)MF * 3;            // 65536*16 floats (4 MB)
  int*    pj    = (int*)(pd2 + (size_t)MF * 16);     // 65536*16 ints   (4 MB)
  __bf16* wt2   = (__bf16*)(pj + (size_t)MF * 16);   // 192*384 bf16
  __bf16* wt1   = wt2 + (size_t)COUT * CIN;          // 192*192 bf16

  k0_prep<<<(CIN * COUT + COUT * COUT) / 256, 256, 0, stream>>>(w2, w1, wt2, wt1);
  k1_ln_gemm<<<MT / 64, 256, 0, stream>>>(feats, ln2_g, ln2_b, wt2, b2, h);
  k2a_knn_part<<<(MF / 256) * NSEG, 256, 0, stream>>>(xyz, sxyz, pd2, pj);
  k2b_knn_merge<<<MF / 256, 256, 0, stream>>>(pd2, pj, knn_i, knn_w);
  k3_ln_gemm_interp<<<MF / 64, 256, 0, stream>>>(sfeats, ln1_g, ln1_b, wt1, b1,
                                                 h, knn_i, knn_w, out);
  k4_tail<<<(MF * 3) / 256, 256, 0, stream>>>(sxyz, soff, out + (size_t)MF * COUT);
}